// Round 2
// baseline (204.663 us; speedup 1.0000x reference)
//
#include <hip/hip_runtime.h>
#include <hip/hip_bf16.h>
#include <hip/hip_fp16.h>

#define FEAT 2048
#define NCLS 751
#define NPAD 768
#define NPRB 64
#define NGAL 256
#define WSCALE 256.0f

typedef _Float16 f16x8 __attribute__((ext_vector_type(8)));
typedef float f32x4 __attribute__((ext_vector_type(4)));

__device__ __forceinline__ unsigned short f2h_u(float x) {
  union { _Float16 h; unsigned short u; } v;
  v.h = (_Float16)x;
  return v.u;
}

// ---------------------------------------------------------------------------
// Kernel 1: per-feature moments of probe/gallery -> BN scale s[f], shift t[f]
// mean[f] = E_pg[(p-g)^2] = M2p - 2 M1p M1g + M2g   (exact, cross-product)
// E[d^2]  = M4p - 4 M3p M1g + 6 M2p M2g - 4 M1p M3g + M4g
// ---------------------------------------------------------------------------
__global__ void stats_kernel(const float* __restrict__ P, const float* __restrict__ G,
                             const float* __restrict__ gamma, const float* __restrict__ beta,
                             float* __restrict__ st) {
  int fx = threadIdx.x & 31, ry = threadIdx.x >> 5;
  int f = blockIdx.x * 32 + fx;
  float a1 = 0, a2 = 0, a3 = 0, a4 = 0;
  for (int r = ry; r < NPRB; r += 8) {
    float x = P[r * FEAT + f], x2 = x * x;
    a1 += x; a2 += x2; a3 += x2 * x; a4 += x2 * x2;
  }
  float b1 = 0, b2 = 0, b3 = 0, b4 = 0;
  for (int r = ry; r < NGAL; r += 8) {
    float x = G[r * FEAT + f], x2 = x * x;
    b1 += x; b2 += x2; b3 += x2 * x; b4 += x2 * x2;
  }
  __shared__ float red[8][8][32];
  float vals[8] = {a1, a2, a3, a4, b1, b2, b3, b4};
#pragma unroll
  for (int m = 0; m < 8; ++m) red[m][ry][fx] = vals[m];
  __syncthreads();
  if (ry == 0) {
    float mm[8];
#pragma unroll
    for (int m = 0; m < 8; ++m) {
      float sum = 0.f;
#pragma unroll
      for (int r = 0; r < 8; ++r) sum += red[m][r][fx];
      mm[m] = sum;
    }
    float M1p = mm[0] * (1.f / NPRB), M2p = mm[1] * (1.f / NPRB);
    float M3p = mm[2] * (1.f / NPRB), M4p = mm[3] * (1.f / NPRB);
    float M1g = mm[4] * (1.f / NGAL), M2g = mm[5] * (1.f / NGAL);
    float M3g = mm[6] * (1.f / NGAL), M4g = mm[7] * (1.f / NGAL);
    float mean = M2p - 2.f * M1p * M1g + M2g;
    float Ed2 = M4p - 4.f * M3p * M1g + 6.f * M2p * M2g - 4.f * M1p * M3g + M4g;
    float var = Ed2 - mean * mean;
    float sv = gamma[f] / sqrtf(var + 1e-5f);
    st[f] = sv;
    st[FEAT + f] = beta[f] - mean * sv;  // t[f]
  }
}

// ---------------------------------------------------------------------------
// Kernel 2 (fused): per class c:
//   Wp[c,f] = W[c,f] * s[f] * WSCALE (f16), bp[c] = b[c] + sum_f t[f] W[c,f]
// ---------------------------------------------------------------------------
__global__ void prepw_kernel(const float* __restrict__ W, const float* __restrict__ b,
                             const float* __restrict__ st,
                             unsigned short* __restrict__ Wp, float* __restrict__ bp) {
  int c = blockIdx.x;
  int f = threadIdx.x * 8;
  float4 w0 = make_float4(0.f, 0.f, 0.f, 0.f), w1 = w0;
  if (c < NCLS) {
    const float4* wsrc = (const float4*)(W + (size_t)c * FEAT + f);
    w0 = wsrc[0]; w1 = wsrc[1];
  }
  const float4* s4 = (const float4*)(st + f);
  float4 s0 = s4[0], s1 = s4[1];
  const float4* t4 = (const float4*)(st + FEAT + f);
  float4 t0 = t4[0], t1 = t4[1];
  uint4 u;
  u.x = (unsigned int)f2h_u(w0.x * s0.x * WSCALE) | ((unsigned int)f2h_u(w0.y * s0.y * WSCALE) << 16);
  u.y = (unsigned int)f2h_u(w0.z * s0.z * WSCALE) | ((unsigned int)f2h_u(w0.w * s0.w * WSCALE) << 16);
  u.z = (unsigned int)f2h_u(w1.x * s1.x * WSCALE) | ((unsigned int)f2h_u(w1.y * s1.y * WSCALE) << 16);
  u.w = (unsigned int)f2h_u(w1.z * s1.z * WSCALE) | ((unsigned int)f2h_u(w1.w * s1.w * WSCALE) << 16);
  *(uint4*)(Wp + (size_t)c * FEAT + f) = u;
  float acc = t0.x * w0.x + t0.y * w0.y + t0.z * w0.z + t0.w * w0.w +
              t1.x * w1.x + t1.y * w1.y + t1.z * w1.z + t1.w * w1.w;
#pragma unroll
  for (int off = 32; off > 0; off >>= 1) acc += __shfl_down(acc, off, 64);
  __shared__ float r[4];
  int wave = threadIdx.x >> 6, lane = threadIdx.x & 63;
  if (lane == 0) r[wave] = acc;
  __syncthreads();
  if (threadIdx.x == 0) bp[c] = (c < NCLS ? b[c] : 0.f) + r[0] + r[1] + r[2] + r[3];
}

// ---------------------------------------------------------------------------
// Kernel 3 (fused GEMM, 2-phase double-buffered pipeline):
// out = BN((P-G)^2) @ W'^T + b'. M=16384, N=768, K=2048, BK=64.
// Per K-step (ONE barrier): issue G(t+1) reg-loads + B(t+1) global_load_lds
// into buf^1, ds_read P-chunk(t+1); ds_read frags from buf + MFMA (setprio);
// then A-gen(t+1) -> ds_write buf^1; __syncthreads. Nothing needs to survive
// the barrier: all drained ops were issued a full MFMA phase (~800cy) before
// the drain point, covering L2 latency (~300cy). A-gen VALU (~520cy/CU/step)
// hides under the MFMA pipe (~1242cy/CU/step) via the alternate buffer.
// ---------------------------------------------------------------------------
__global__ __launch_bounds__(256, 2)
void gemm_fused_kernel(const float* __restrict__ P, const float* __restrict__ G,
                       const unsigned short* __restrict__ Wp,
                       const float* __restrict__ bp, float* __restrict__ out) {
  __shared__ unsigned short As[2][128 * 64];  // 2 x 16 KB: f16 (p-g)^2 tiles
  __shared__ unsigned short Bs[2][128 * 64];  // 2 x 16 KB: f16 W' tiles
  __shared__ float Ps[FEAT];                  // 8 KB: this block's P row (f32)

  const int tid = threadIdx.x;
  const int lane = tid & 63, wave = tid >> 6;
  const int mtile = blockIdx.x, ntile = blockIdx.y;
  const int p = mtile >> 1;

  // staging roles: thread t -> LDS rows srow+32j, slot t&7; slot s of row r
  // holds global k-chunk s^(r&7)  => this thread sources chunk sch.
  const int srow = tid >> 3;                      // 0..31
  const int sch = (tid & 7) ^ (srow & 7);         // source k-chunk
  const float* gp = G + (size_t)((mtile & 1) * 128 + srow) * FEAT + sch * 8;
  const unsigned short* bg = Wp + (size_t)(ntile * 128 + srow) * FEAT + sch * 8;
  const int aswo = srow * 64 + (tid & 7) * 8;     // ds_write elem offset in an As buf
  const int bldo = wave * 1024;                   // byte offset in a Bs buf (HW adds lane*16)

  // ---- prologue ----
  {  // P row -> LDS (f32)
    const float4* psrc = (const float4*)(P + (size_t)p * FEAT) + tid * 2;
    float4 pa = psrc[0], pb = psrc[1];
    float4* pd = (float4*)Ps + tid * 2;
    pd[0] = pa; pd[1] = pb;
  }
#pragma unroll
  for (int j = 0; j < 4; ++j)  // B(0) -> Bs[0]
    __builtin_amdgcn_global_load_lds(
        (const __attribute__((address_space(1))) void*)(bg + (size_t)j * 32 * FEAT),
        (__attribute__((address_space(3))) void*)((char*)Bs[0] + bldo + j * 4096), 16, 0, 0);
  float4 g0[4], g1[4];
#pragma unroll
  for (int j = 0; j < 4; ++j) {  // G(0) -> regs
    const float4* gs = (const float4*)(gp + (size_t)j * 32 * FEAT);
    g0[j] = gs[0]; g1[j] = gs[1];
  }
  __syncthreads();  // Ps visible (also drains B(0), G(0))

  {  // A(0) gen -> As[0]
    const float* pr = Ps + sch * 8;
    float4 p0 = *(const float4*)pr;
    float4 p1 = *(const float4*)(pr + 4);
#pragma unroll
    for (int j = 0; j < 4; ++j) {
      float d0 = p0.x - g0[j].x, d1 = p0.y - g0[j].y;
      float d2 = p0.z - g0[j].z, d3 = p0.w - g0[j].w;
      float d4 = p1.x - g1[j].x, d5 = p1.y - g1[j].y;
      float d6 = p1.z - g1[j].z, d7 = p1.w - g1[j].w;
      uint4 u;
      u.x = (unsigned int)f2h_u(d0 * d0) | ((unsigned int)f2h_u(d1 * d1) << 16);
      u.y = (unsigned int)f2h_u(d2 * d2) | ((unsigned int)f2h_u(d3 * d3) << 16);
      u.z = (unsigned int)f2h_u(d4 * d4) | ((unsigned int)f2h_u(d5 * d5) << 16);
      u.w = (unsigned int)f2h_u(d6 * d6) | ((unsigned int)f2h_u(d7 * d7) << 16);
      *(uint4*)(As[0] + aswo + j * 32 * 64) = u;
    }
  }
  __syncthreads();  // A(0) visible

  f32x4 acc[4][4];
#pragma unroll
  for (int mi = 0; mi < 4; ++mi)
#pragma unroll
    for (int ni = 0; ni < 4; ++ni) acc[mi][ni] = (f32x4){0.f, 0.f, 0.f, 0.f};

  const int wm = (wave & 1) * 64, wn = (wave >> 1) * 64;
  const int frow = lane & 15, fsw = lane & 7, fk = lane >> 4;  // fragment roles

  // ---- main loop: one barrier per K-step ----
  int cur = 0;
  for (int t = 0; t < 32; ++t) {
    const int k0 = t * 64;
    const bool has_next = (t < 31);
    float4 p0n, p1n;

    if (has_next) {
      // 1. G(t+1) -> regs (consumed AFTER the MFMA cluster; vmcnt wait lands there)
#pragma unroll
      for (int j = 0; j < 4; ++j) {
        const float4* gs = (const float4*)(gp + k0 + 64 + (size_t)j * 32 * FEAT);
        g0[j] = gs[0]; g1[j] = gs[1];
      }
      // 2. B(t+1) -> Bs[cur^1] (drained by the end-of-iteration barrier)
#pragma unroll
      for (int j = 0; j < 4; ++j)
        __builtin_amdgcn_global_load_lds(
            (const __attribute__((address_space(1))) void*)(bg + k0 + 64 + (size_t)j * 32 * FEAT),
            (__attribute__((address_space(3))) void*)((char*)Bs[cur ^ 1] + bldo + j * 4096), 16, 0, 0);
      // 3. P chunk (t+1)
      const float* prn = Ps + k0 + 64 + sch * 8;
      p0n = *(const float4*)prn;
      p1n = *(const float4*)(prn + 4);
    }

    // 4. fragments + MFMA on buffer `cur`
    __builtin_amdgcn_s_setprio(1);
#pragma unroll
    for (int kk = 0; kk < 2; ++kk) {
      const int slot = (kk * 4 + fk) ^ fsw;  // LDS slot holding k-chunk kk*4+fk
      f16x8 af[4], bf[4];
#pragma unroll
      for (int mi = 0; mi < 4; ++mi)
        af[mi] = *(const f16x8*)(As[cur] + (wm + mi * 16 + frow) * 64 + slot * 8);
#pragma unroll
      for (int ni = 0; ni < 4; ++ni)
        bf[ni] = *(const f16x8*)(Bs[cur] + (wn + ni * 16 + frow) * 64 + slot * 8);
#pragma unroll
      for (int mi = 0; mi < 4; ++mi)
#pragma unroll
        for (int ni = 0; ni < 4; ++ni)
          acc[mi][ni] = __builtin_amdgcn_mfma_f32_16x16x32_f16(af[mi], bf[ni], acc[mi][ni], 0, 0, 0);
    }
    __builtin_amdgcn_s_setprio(0);

    // 5. A-gen(t+1) -> As[cur^1] (G reg loads drain here, under MFMA shadow)
    if (has_next) {
#pragma unroll
      for (int j = 0; j < 4; ++j) {
        float d0 = p0n.x - g0[j].x, d1 = p0n.y - g0[j].y;
        float d2 = p0n.z - g0[j].z, d3 = p0n.w - g0[j].w;
        float d4 = p1n.x - g1[j].x, d5 = p1n.y - g1[j].y;
        float d6 = p1n.z - g1[j].z, d7 = p1n.w - g1[j].w;
        uint4 u;
        u.x = (unsigned int)f2h_u(d0 * d0) | ((unsigned int)f2h_u(d1 * d1) << 16);
        u.y = (unsigned int)f2h_u(d2 * d2) | ((unsigned int)f2h_u(d3 * d3) << 16);
        u.z = (unsigned int)f2h_u(d4 * d4) | ((unsigned int)f2h_u(d5 * d5) << 16);
        u.w = (unsigned int)f2h_u(d6 * d6) | ((unsigned int)f2h_u(d7 * d7) << 16);
        *(uint4*)(As[cur ^ 1] + aswo + j * 32 * 64) = u;
      }
    }

    __syncthreads();  // single drain point: B(t+1) landed, A(t+1) visible
    cur ^= 1;
  }

  // epilogue: C/D layout col=lane&15, row=(lane>>4)*4+reg; undo WSCALE, add b'
  const int col0 = ntile * 128 + wn + (lane & 15);
  const int row0 = mtile * 128 + wm + ((lane >> 4) << 2);
#pragma unroll
  for (int ni = 0; ni < 4; ++ni) {
    int col = col0 + ni * 16;
    if (col >= NCLS) continue;
    float bv = bp[col];
#pragma unroll
    for (int mi = 0; mi < 4; ++mi) {
      int row = row0 + mi * 16;
#pragma unroll
      for (int r = 0; r < 4; ++r)
        out[(size_t)(row + r) * NCLS + col] = acc[mi][ni][r] * (1.0f / WSCALE) + bv;
    }
  }
}

// ---------------------------------------------------------------------------
extern "C" void kernel_launch(void* const* d_in, const int* in_sizes, int n_in,
                              void* d_out, int out_size, void* d_ws, size_t ws_size,
                              hipStream_t stream) {
  const float* P = (const float*)d_in[0];
  const float* G = (const float*)d_in[1];
  const float* gamma = (const float*)d_in[2];
  const float* beta = (const float*)d_in[3];
  const float* W = (const float*)d_in[4];
  const float* b = (const float*)d_in[5];
  float* out = (float*)d_out;

  float* st = (float*)d_ws;                           // s[2048], t[2048]
  float* bp = st + 2 * FEAT;                          // b'[768]
  unsigned short* Wp = (unsigned short*)(bp + NPAD);  // f16 W' [768, 2048]

  hipLaunchKernelGGL(stats_kernel, dim3(64), dim3(256), 0, stream, P, G, gamma, beta, st);
  hipLaunchKernelGGL(prepw_kernel, dim3(NPAD), dim3(256), 0, stream, W, b, st, Wp, bp);
  hipLaunchKernelGGL(gemm_fused_kernel, dim3(128, 6), dim3(256), 0, stream, P, G, Wp, bp, out);
}

// Round 3
// 170.017 us; speedup vs baseline: 1.2038x; 1.2038x over previous
//
#include <hip/hip_runtime.h>
#include <hip/hip_bf16.h>
#include <hip/hip_fp16.h>

#define FEAT 2048
#define NCLS 751
#define NPAD 768
#define NPRB 64
#define NGAL 256
#define WSCALE 256.0f

typedef _Float16 f16x8 __attribute__((ext_vector_type(8)));
typedef float f32x4 __attribute__((ext_vector_type(4)));

__device__ __forceinline__ unsigned short f2h_u(float x) {
  union { _Float16 h; unsigned short u; } v;
  v.h = (_Float16)x;
  return v.u;
}

// ---------------------------------------------------------------------------
// Kernel 1: per-feature moments -> BN scale s[f], shift t[f].
// Rewritten for parallelism: 256 blocks x (8 features x 32 row-lanes).
// Old version: 64 blocks, 40 serial strided loads/thread -> latency-bound.
// Now: 4x blocks, 10 serial loads/thread.
// mean[f] = M2p - 2 M1p M1g + M2g ; E[d^2] = M4p - 4M3p M1g + 6M2p M2g - 4M1p M3g + M4g
// ---------------------------------------------------------------------------
__global__ __launch_bounds__(256)
void stats_kernel(const float* __restrict__ P, const float* __restrict__ G,
                  const float* __restrict__ gamma, const float* __restrict__ beta,
                  float* __restrict__ st) {
  const int t = threadIdx.x;
  const int fx = t & 7, ry = t >> 3;          // 8 features x 32 row-lanes
  const int f = blockIdx.x * 8 + fx;
  float a1 = 0, a2 = 0, a3 = 0, a4 = 0;
#pragma unroll
  for (int r = ry; r < NPRB; r += 32) {       // 2 iters
    float x = P[r * FEAT + f], x2 = x * x;
    a1 += x; a2 += x2; a3 += x2 * x; a4 += x2 * x2;
  }
  float b1 = 0, b2 = 0, b3 = 0, b4 = 0;
#pragma unroll
  for (int r = ry; r < NGAL; r += 32) {       // 8 iters
    float x = G[r * FEAT + f], x2 = x * x;
    b1 += x; b2 += x2; b3 += x2 * x; b4 += x2 * x2;
  }
  __shared__ float red[8][32][8];   // [moment][ry][fx]
  __shared__ float red2[8][4][8];   // [moment][quarter][fx]
  float vals[8] = {a1, a2, a3, a4, b1, b2, b3, b4};
#pragma unroll
  for (int m = 0; m < 8; ++m) red[m][ry][fx] = vals[m];
  __syncthreads();
  {
    int m = t >> 5, q = (t >> 3) & 3, fx2 = t & 7;
    float s = 0.f;
#pragma unroll
    for (int r = 0; r < 8; ++r) s += red[m][q * 8 + r][fx2];
    red2[m][q][fx2] = s;
  }
  __syncthreads();
  if (t < 8) {
    float mm[8];
#pragma unroll
    for (int m = 0; m < 8; ++m)
      mm[m] = red2[m][0][t] + red2[m][1][t] + red2[m][2][t] + red2[m][3][t];
    float M1p = mm[0] * (1.f / NPRB), M2p = mm[1] * (1.f / NPRB);
    float M3p = mm[2] * (1.f / NPRB), M4p = mm[3] * (1.f / NPRB);
    float M1g = mm[4] * (1.f / NGAL), M2g = mm[5] * (1.f / NGAL);
    float M3g = mm[6] * (1.f / NGAL), M4g = mm[7] * (1.f / NGAL);
    float mean = M2p - 2.f * M1p * M1g + M2g;
    float Ed2 = M4p - 4.f * M3p * M1g + 6.f * M2p * M2g - 4.f * M1p * M3g + M4g;
    float var = Ed2 - mean * mean;
    int ff = blockIdx.x * 8 + t;
    float sv = gamma[ff] / sqrtf(var + 1e-5f);
    st[ff] = sv;
    st[FEAT + ff] = beta[ff] - mean * sv;  // t[f]
  }
}

// ---------------------------------------------------------------------------
// Kernel 2 (fused): per class c:
//   Wp[c,f] = W[c,f] * s[f] * WSCALE (f16), bp[c] = b[c] + sum_f t[f] W[c,f]
// ---------------------------------------------------------------------------
__global__ void prepw_kernel(const float* __restrict__ W, const float* __restrict__ b,
                             const float* __restrict__ st,
                             unsigned short* __restrict__ Wp, float* __restrict__ bp) {
  int c = blockIdx.x;
  int f = threadIdx.x * 8;
  float4 w0 = make_float4(0.f, 0.f, 0.f, 0.f), w1 = w0;
  if (c < NCLS) {
    const float4* wsrc = (const float4*)(W + (size_t)c * FEAT + f);
    w0 = wsrc[0]; w1 = wsrc[1];
  }
  const float4* s4 = (const float4*)(st + f);
  float4 s0 = s4[0], s1 = s4[1];
  const float4* t4 = (const float4*)(st + FEAT + f);
  float4 t0 = t4[0], t1 = t4[1];
  uint4 u;
  u.x = (unsigned int)f2h_u(w0.x * s0.x * WSCALE) | ((unsigned int)f2h_u(w0.y * s0.y * WSCALE) << 16);
  u.y = (unsigned int)f2h_u(w0.z * s0.z * WSCALE) | ((unsigned int)f2h_u(w0.w * s0.w * WSCALE) << 16);
  u.z = (unsigned int)f2h_u(w1.x * s1.x * WSCALE) | ((unsigned int)f2h_u(w1.y * s1.y * WSCALE) << 16);
  u.w = (unsigned int)f2h_u(w1.z * s1.z * WSCALE) | ((unsigned int)f2h_u(w1.w * s1.w * WSCALE) << 16);
  *(uint4*)(Wp + (size_t)c * FEAT + f) = u;
  float acc = t0.x * w0.x + t0.y * w0.y + t0.z * w0.z + t0.w * w0.w +
              t1.x * w1.x + t1.y * w1.y + t1.z * w1.z + t1.w * w1.w;
#pragma unroll
  for (int off = 32; off > 0; off >>= 1) acc += __shfl_down(acc, off, 64);
  __shared__ float r[4];
  int wave = threadIdx.x >> 6, lane = threadIdx.x & 63;
  if (lane == 0) r[wave] = acc;
  __syncthreads();
  if (threadIdx.x == 0) bp[c] = (c < NCLS ? b[c] : 0.f) + r[0] + r[1] + r[2] + r[3];
}

// ---------------------------------------------------------------------------
// Kernel 3 (fused GEMM, BK=32 double-buffered 1-barrier pipeline):
// out = BN((P-G)^2) @ W'^T + b'. M=16384, N=768, K=2048.
// Round-2 lesson: 72KB LDS -> 2 blk/CU -> 768 blocks ran in 2 rounds (1.5x).
// Now As[2]+Bs[2] (BK=32) + Ps = 44KB (padded) -> exactly 3 blk/CU, all 768
// blocks co-resident, 3 independent barrier phases per SIMD fill the MFMA pipe.
// Per K-step (ONE barrier): issue G(t+1) reg-loads, B(t+1) global_load_lds
// into buf^1, Ps chunk(t+1); frags+MFMA on buf (setprio); A-gen(t+1) ->
// ds_write buf^1 (G vmcnt drains here, under MFMA shadow); __syncthreads.
// 4-slot XOR swizzle (slot = chunk ^ (row&3)) keeps b128 frag reads uniform
// over all 8 bank-quads (conflict-free in aggregate).
// ---------------------------------------------------------------------------
__global__ __launch_bounds__(256, 3)
void gemm_fused_kernel(const float* __restrict__ P, const float* __restrict__ G,
                       const unsigned short* __restrict__ Wp,
                       const float* __restrict__ bp, float* __restrict__ out) {
  __shared__ unsigned short As[2][128 * 32];  // 2 x 8 KB: f16 (p-g)^2 tiles
  __shared__ unsigned short Bs[2][128 * 32];  // 2 x 8 KB: f16 W' tiles
  __shared__ float Ps[3072];                  // 8 KB used + 4 KB pad -> 44 KB total
                                              // (forces max 3 blk/CU: even 3/3/3 split)

  const int tid = threadIdx.x;
  const int lane = tid & 63, wave = tid >> 6;
  const int mtile = blockIdx.x, ntile = blockIdx.y;
  const int p = mtile >> 1;

  // A-gen roles: thread -> row = tid>>1 (0..127), h = tid&1 (k-half of 32).
  // Computes global chunks c0=2h, c0+1; writes slot c^(row&3) (writer swizzle).
  const int arow = tid >> 1, ah = tid & 1;
  const float* gp = G + (size_t)((mtile & 1) * 128 + arow) * FEAT + ah * 16;
  const int aslot0 = (2 * ah) ^ (arow & 3);

  // B staging (global_load_lds, 2 insts x 4KB): inst j dest elem j*2048+t*8
  // -> row = j*64 + (t>>2), slot = t&3 => source chunk (t&3)^((t>>2)&3).
  const int brow = tid >> 2;
  const int bch = (tid & 3) ^ (brow & 3);
  const unsigned short* bg = Wp + (size_t)(ntile * 128 + brow) * FEAT + bch * 8;
  const int bldo = wave * 1024;  // byte offset in a Bs buf (HW adds lane*16)

  // ---- prologue ----
  {  // P row -> LDS (f32)
    const float4* psrc = (const float4*)(P + (size_t)p * FEAT) + tid * 2;
    float4 pa = psrc[0], pb = psrc[1];
    ((float4*)Ps)[tid * 2] = pa;
    ((float4*)Ps)[tid * 2 + 1] = pb;
  }
  float4 g[4];  // G(0) -> regs (issue before B so A-gen's wait leaves B in flight)
#pragma unroll
  for (int j = 0; j < 4; ++j) g[j] = ((const float4*)gp)[j];
#pragma unroll
  for (int j = 0; j < 2; ++j)  // B(0) -> Bs[0]
    __builtin_amdgcn_global_load_lds(
        (const __attribute__((address_space(1))) void*)(bg + (size_t)j * 64 * FEAT),
        (__attribute__((address_space(3))) void*)((char*)Bs[0] + j * 4096 + bldo), 16, 0, 0);
  __syncthreads();  // Ps visible; G(0), B(0) drained

  {  // A(0) -> As[0]
    const float* pr = Ps + ah * 16;
    float4 p0 = ((const float4*)pr)[0], p1 = ((const float4*)pr)[1];
    float4 p2 = ((const float4*)pr)[2], p3 = ((const float4*)pr)[3];
    float d0 = p0.x - g[0].x, d1 = p0.y - g[0].y, d2 = p0.z - g[0].z, d3 = p0.w - g[0].w;
    float d4 = p1.x - g[1].x, d5 = p1.y - g[1].y, d6 = p1.z - g[1].z, d7 = p1.w - g[1].w;
    float e0 = p2.x - g[2].x, e1 = p2.y - g[2].y, e2 = p2.z - g[2].z, e3 = p2.w - g[2].w;
    float e4 = p3.x - g[3].x, e5 = p3.y - g[3].y, e6 = p3.z - g[3].z, e7 = p3.w - g[3].w;
    uint4 ua, ub;
    ua.x = (unsigned int)f2h_u(d0 * d0) | ((unsigned int)f2h_u(d1 * d1) << 16);
    ua.y = (unsigned int)f2h_u(d2 * d2) | ((unsigned int)f2h_u(d3 * d3) << 16);
    ua.z = (unsigned int)f2h_u(d4 * d4) | ((unsigned int)f2h_u(d5 * d5) << 16);
    ua.w = (unsigned int)f2h_u(d6 * d6) | ((unsigned int)f2h_u(d7 * d7) << 16);
    ub.x = (unsigned int)f2h_u(e0 * e0) | ((unsigned int)f2h_u(e1 * e1) << 16);
    ub.y = (unsigned int)f2h_u(e2 * e2) | ((unsigned int)f2h_u(e3 * e3) << 16);
    ub.z = (unsigned int)f2h_u(e4 * e4) | ((unsigned int)f2h_u(e5 * e5) << 16);
    ub.w = (unsigned int)f2h_u(e6 * e6) | ((unsigned int)f2h_u(e7 * e7) << 16);
    unsigned short* ab = As[0] + arow * 32;
    *(uint4*)(ab + aslot0 * 8) = ua;
    *(uint4*)(ab + (aslot0 ^ 1) * 8) = ub;
  }
  __syncthreads();  // A(0) visible

  f32x4 acc[4][4];
#pragma unroll
  for (int mi = 0; mi < 4; ++mi)
#pragma unroll
    for (int ni = 0; ni < 4; ++ni) acc[mi][ni] = (f32x4){0.f, 0.f, 0.f, 0.f};

  const int wm = (wave & 1) * 64, wn = (wave >> 1) * 64;
  const int frow = lane & 15, fk = lane >> 4;
  const int fslot = fk ^ (frow & 3);  // row&3 == frow&3 for all frag rows

  // ---- main loop: 64 K-steps, one barrier each ----
  int cur = 0;
  for (int t = 0; t < 64; ++t) {
    const int k0 = t * 32;
    const bool hn = (t < 63);
    float4 pn0, pn1, pn2, pn3;

    if (hn) {
      // 1. G(t+1) -> regs (consumed after MFMA; vmcnt wait lands under its shadow)
      const float* gn = gp + k0 + 32;
#pragma unroll
      for (int j = 0; j < 4; ++j) g[j] = ((const float4*)gn)[j];
      // 2. B(t+1) -> Bs[cur^1] (drained by end-of-iteration barrier)
#pragma unroll
      for (int j = 0; j < 2; ++j)
        __builtin_amdgcn_global_load_lds(
            (const __attribute__((address_space(1))) void*)(bg + k0 + 32 + (size_t)j * 64 * FEAT),
            (__attribute__((address_space(3))) void*)((char*)Bs[cur ^ 1] + j * 4096 + bldo), 16, 0, 0);
      // 3. P chunk(t+1)
      const float* prn = Ps + k0 + 32 + ah * 16;
      pn0 = ((const float4*)prn)[0]; pn1 = ((const float4*)prn)[1];
      pn2 = ((const float4*)prn)[2]; pn3 = ((const float4*)prn)[3];
    }

    // 4. fragments + MFMA on buffer `cur`
    __builtin_amdgcn_s_setprio(1);
    {
      f16x8 af[4], bf[4];
#pragma unroll
      for (int mi = 0; mi < 4; ++mi)
        af[mi] = *(const f16x8*)(As[cur] + (wm + mi * 16 + frow) * 32 + fslot * 8);
#pragma unroll
      for (int ni = 0; ni < 4; ++ni)
        bf[ni] = *(const f16x8*)(Bs[cur] + (wn + ni * 16 + frow) * 32 + fslot * 8);
#pragma unroll
      for (int mi = 0; mi < 4; ++mi)
#pragma unroll
        for (int ni = 0; ni < 4; ++ni)
          acc[mi][ni] = __builtin_amdgcn_mfma_f32_16x16x32_f16(af[mi], bf[ni], acc[mi][ni], 0, 0, 0);
    }
    __builtin_amdgcn_s_setprio(0);

    // 5. A-gen(t+1) -> As[cur^1] (under the MFMA shadow of other blocks)
    if (hn) {
      float d0 = pn0.x - g[0].x, d1 = pn0.y - g[0].y, d2 = pn0.z - g[0].z, d3 = pn0.w - g[0].w;
      float d4 = pn1.x - g[1].x, d5 = pn1.y - g[1].y, d6 = pn1.z - g[1].z, d7 = pn1.w - g[1].w;
      float e0 = pn2.x - g[2].x, e1 = pn2.y - g[2].y, e2 = pn2.z - g[2].z, e3 = pn2.w - g[2].w;
      float e4 = pn3.x - g[3].x, e5 = pn3.y - g[3].y, e6 = pn3.z - g[3].z, e7 = pn3.w - g[3].w;
      uint4 ua, ub;
      ua.x = (unsigned int)f2h_u(d0 * d0) | ((unsigned int)f2h_u(d1 * d1) << 16);
      ua.y = (unsigned int)f2h_u(d2 * d2) | ((unsigned int)f2h_u(d3 * d3) << 16);
      ua.z = (unsigned int)f2h_u(d4 * d4) | ((unsigned int)f2h_u(d5 * d5) << 16);
      ua.w = (unsigned int)f2h_u(d6 * d6) | ((unsigned int)f2h_u(d7 * d7) << 16);
      ub.x = (unsigned int)f2h_u(e0 * e0) | ((unsigned int)f2h_u(e1 * e1) << 16);
      ub.y = (unsigned int)f2h_u(e2 * e2) | ((unsigned int)f2h_u(e3 * e3) << 16);
      ub.z = (unsigned int)f2h_u(e4 * e4) | ((unsigned int)f2h_u(e5 * e5) << 16);
      ub.w = (unsigned int)f2h_u(e6 * e6) | ((unsigned int)f2h_u(e7 * e7) << 16);
      unsigned short* ab = As[cur ^ 1] + arow * 32;
      *(uint4*)(ab + aslot0 * 8) = ua;
      *(uint4*)(ab + (aslot0 ^ 1) * 8) = ub;
    }

    __syncthreads();  // single drain point: B(t+1) landed, A(t+1) visible
    cur ^= 1;
  }

  // epilogue: C/D layout col=lane&15, row=(lane>>4)*4+reg; undo WSCALE, add b'
  const int col0 = ntile * 128 + wn + (lane & 15);
  const int row0 = mtile * 128 + wm + ((lane >> 4) << 2);
#pragma unroll
  for (int ni = 0; ni < 4; ++ni) {
    int col = col0 + ni * 16;
    if (col >= NCLS) continue;
    float bv = bp[col];
#pragma unroll
    for (int mi = 0; mi < 4; ++mi) {
      int row = row0 + mi * 16;
#pragma unroll
      for (int r = 0; r < 4; ++r)
        out[(size_t)(row + r) * NCLS + col] = acc[mi][ni][r] * (1.0f / WSCALE) + bv;
    }
  }
}

// ---------------------------------------------------------------------------
extern "C" void kernel_launch(void* const* d_in, const int* in_sizes, int n_in,
                              void* d_out, int out_size, void* d_ws, size_t ws_size,
                              hipStream_t stream) {
  const float* P = (const float*)d_in[0];
  const float* G = (const float*)d_in[1];
  const float* gamma = (const float*)d_in[2];
  const float* beta = (const float*)d_in[3];
  const float* W = (const float*)d_in[4];
  const float* b = (const float*)d_in[5];
  float* out = (float*)d_out;

  float* st = (float*)d_ws;                           // s[2048], t[2048]
  float* bp = st + 2 * FEAT;                          // b'[768]
  unsigned short* Wp = (unsigned short*)(bp + NPAD);  // f16 W' [768, 2048]

  hipLaunchKernelGGL(stats_kernel, dim3(256), dim3(256), 0, stream, P, G, gamma, beta, st);
  hipLaunchKernelGGL(prepw_kernel, dim3(NPAD), dim3(256), 0, stream, W, b, st, Wp, bp);
  hipLaunchKernelGGL(gemm_fused_kernel, dim3(128, 6), dim3(256), 0, stream, P, G, Wp, bp, out);
}

// Round 4
// 167.046 us; speedup vs baseline: 1.2252x; 1.0178x over previous
//
#include <hip/hip_runtime.h>
#include <hip/hip_bf16.h>
#include <hip/hip_fp16.h>

#define FEAT 2048
#define NCLS 751
#define NPAD 768
#define NPRB 64
#define NGAL 256
#define WSCALE 256.0f

typedef _Float16 f16x8 __attribute__((ext_vector_type(8)));
typedef float f32x4 __attribute__((ext_vector_type(4)));

__device__ __forceinline__ unsigned short f2h_u(float x) {
  union { _Float16 h; unsigned short u; } v;
  v.h = (_Float16)x;
  return v.u;
}

// ---------------------------------------------------------------------------
// Kernel 1: per-feature moments -> BN scale s[f], shift t[f].
// 256 blocks x (8 features x 32 row-lanes).
// mean[f] = M2p - 2 M1p M1g + M2g ; E[d^2] = M4p - 4M3p M1g + 6M2p M2g - 4M1p M3g + M4g
// ---------------------------------------------------------------------------
__global__ __launch_bounds__(256)
void stats_kernel(const float* __restrict__ P, const float* __restrict__ G,
                  const float* __restrict__ gamma, const float* __restrict__ beta,
                  float* __restrict__ st) {
  const int t = threadIdx.x;
  const int fx = t & 7, ry = t >> 3;          // 8 features x 32 row-lanes
  const int f = blockIdx.x * 8 + fx;
  float a1 = 0, a2 = 0, a3 = 0, a4 = 0;
#pragma unroll
  for (int r = ry; r < NPRB; r += 32) {       // 2 iters
    float x = P[r * FEAT + f], x2 = x * x;
    a1 += x; a2 += x2; a3 += x2 * x; a4 += x2 * x2;
  }
  float b1 = 0, b2 = 0, b3 = 0, b4 = 0;
#pragma unroll
  for (int r = ry; r < NGAL; r += 32) {       // 8 iters
    float x = G[r * FEAT + f], x2 = x * x;
    b1 += x; b2 += x2; b3 += x2 * x; b4 += x2 * x2;
  }
  __shared__ float red[8][32][8];   // [moment][ry][fx]
  __shared__ float red2[8][4][8];   // [moment][quarter][fx]
  float vals[8] = {a1, a2, a3, a4, b1, b2, b3, b4};
#pragma unroll
  for (int m = 0; m < 8; ++m) red[m][ry][fx] = vals[m];
  __syncthreads();
  {
    int m = t >> 5, q = (t >> 3) & 3, fx2 = t & 7;
    float s = 0.f;
#pragma unroll
    for (int r = 0; r < 8; ++r) s += red[m][q * 8 + r][fx2];
    red2[m][q][fx2] = s;
  }
  __syncthreads();
  if (t < 8) {
    float mm[8];
#pragma unroll
    for (int m = 0; m < 8; ++m)
      mm[m] = red2[m][0][t] + red2[m][1][t] + red2[m][2][t] + red2[m][3][t];
    float M1p = mm[0] * (1.f / NPRB), M2p = mm[1] * (1.f / NPRB);
    float M3p = mm[2] * (1.f / NPRB), M4p = mm[3] * (1.f / NPRB);
    float M1g = mm[4] * (1.f / NGAL), M2g = mm[5] * (1.f / NGAL);
    float M3g = mm[6] * (1.f / NGAL), M4g = mm[7] * (1.f / NGAL);
    float mean = M2p - 2.f * M1p * M1g + M2g;
    float Ed2 = M4p - 4.f * M3p * M1g + 6.f * M2p * M2g - 4.f * M1p * M3g + M4g;
    float var = Ed2 - mean * mean;
    int ff = blockIdx.x * 8 + t;
    float sv = gamma[ff] / sqrtf(var + 1e-5f);
    st[ff] = sv;
    st[FEAT + ff] = beta[ff] - mean * sv;  // t[f]
  }
}

// ---------------------------------------------------------------------------
// Kernel 2 (fused): per class c:
//   Wp[c,f] = W[c,f] * s[f] * WSCALE (f16), bp[c] = b[c] + sum_f t[f] W[c,f]
// ---------------------------------------------------------------------------
__global__ void prepw_kernel(const float* __restrict__ W, const float* __restrict__ b,
                             const float* __restrict__ st,
                             unsigned short* __restrict__ Wp, float* __restrict__ bp) {
  int c = blockIdx.x;
  int f = threadIdx.x * 8;
  float4 w0 = make_float4(0.f, 0.f, 0.f, 0.f), w1 = w0;
  if (c < NCLS) {
    const float4* wsrc = (const float4*)(W + (size_t)c * FEAT + f);
    w0 = wsrc[0]; w1 = wsrc[1];
  }
  const float4* s4 = (const float4*)(st + f);
  float4 s0 = s4[0], s1 = s4[1];
  const float4* t4 = (const float4*)(st + FEAT + f);
  float4 t0 = t4[0], t1 = t4[1];
  uint4 u;
  u.x = (unsigned int)f2h_u(w0.x * s0.x * WSCALE) | ((unsigned int)f2h_u(w0.y * s0.y * WSCALE) << 16);
  u.y = (unsigned int)f2h_u(w0.z * s0.z * WSCALE) | ((unsigned int)f2h_u(w0.w * s0.w * WSCALE) << 16);
  u.z = (unsigned int)f2h_u(w1.x * s1.x * WSCALE) | ((unsigned int)f2h_u(w1.y * s1.y * WSCALE) << 16);
  u.w = (unsigned int)f2h_u(w1.z * s1.z * WSCALE) | ((unsigned int)f2h_u(w1.w * s1.w * WSCALE) << 16);
  *(uint4*)(Wp + (size_t)c * FEAT + f) = u;
  float acc = t0.x * w0.x + t0.y * w0.y + t0.z * w0.z + t0.w * w0.w +
              t1.x * w1.x + t1.y * w1.y + t1.z * w1.z + t1.w * w1.w;
#pragma unroll
  for (int off = 32; off > 0; off >>= 1) acc += __shfl_down(acc, off, 64);
  __shared__ float r[4];
  int wave = threadIdx.x >> 6, lane = threadIdx.x & 63;
  if (lane == 0) r[wave] = acc;
  __syncthreads();
  if (threadIdx.x == 0) bp[c] = (c < NCLS ? b[c] : 0.f) + r[0] + r[1] + r[2] + r[3];
}

// ---------------------------------------------------------------------------
// Kernel 3 (fused GEMM, BK=32 double-buffered 1-barrier pipeline):
// out = BN((P-G)^2) @ W'^T + b'. M=16384, N=768, K=2048.
// Round-3 lesson: with 64-byte LDS rows, bank-quad = 4*(row&1) + slot, so the
// old slot = chunk ^ (row&3) swizzle left 16-lane read phases hitting only 4
// quads (4-way conflict, 9.5M conflict cycles). Correct swizzle for this
// geometry: slot = chunk ^ ((row>>1)&3) -- any 8 consecutive frag-read lanes
// enumerate all 8 bank-quads exactly once (writes likewise). Verified for all
// three touch points (frag read, A-gen ds_write, B gload-lds source chunk).
// Per K-step (ONE barrier): issue G(t+1) reg-loads, B(t+1) global_load_lds
// into buf^1, Ps chunk(t+1); frags+MFMA on buf (setprio); A-gen(t+1) ->
// ds_write buf^1 (G vmcnt drains here, under MFMA shadow); __syncthreads.
// ---------------------------------------------------------------------------
__global__ __launch_bounds__(256, 3)
void gemm_fused_kernel(const float* __restrict__ P, const float* __restrict__ G,
                       const unsigned short* __restrict__ Wp,
                       const float* __restrict__ bp, float* __restrict__ out) {
  __shared__ unsigned short As[2][128 * 32];  // 2 x 8 KB: f16 (p-g)^2 tiles
  __shared__ unsigned short Bs[2][128 * 32];  // 2 x 8 KB: f16 W' tiles
  __shared__ float Ps[3072];                  // 8 KB used + 4 KB pad -> 44 KB total
                                              // (forces max 3 blk/CU: even 3/3/3 split)

  const int tid = threadIdx.x;
  const int lane = tid & 63, wave = tid >> 6;
  const int mtile = blockIdx.x, ntile = blockIdx.y;
  const int p = mtile >> 1;

  // A-gen roles: thread -> row = tid>>1 (0..127), h = tid&1 (k-half of 32).
  // Computes global chunks c0=2h, c0+1; writes slot c ^ ((row>>1)&3).
  const int arow = tid >> 1, ah = tid & 1;
  const float* gp = G + (size_t)((mtile & 1) * 128 + arow) * FEAT + ah * 16;
  const int aslot0 = (2 * ah) ^ ((arow >> 1) & 3);

  // B staging (global_load_lds, 2 insts x 4KB): dest slot idx = tid + j*256
  // -> row = idx>>2, s = idx&3 => source chunk = (tid&3) ^ ((tid>>3)&3).
  const int brow = tid >> 2;
  const int bch = (tid & 3) ^ ((tid >> 3) & 3);
  const unsigned short* bg = Wp + (size_t)(ntile * 128 + brow) * FEAT + bch * 8;
  const int bldo = wave * 1024;  // byte offset in a Bs buf (HW adds lane*16)

  // ---- prologue ----
  {  // P row -> LDS (f32)
    const float4* psrc = (const float4*)(P + (size_t)p * FEAT) + tid * 2;
    float4 pa = psrc[0], pb = psrc[1];
    ((float4*)Ps)[tid * 2] = pa;
    ((float4*)Ps)[tid * 2 + 1] = pb;
  }
  float4 g[4];  // G(0) -> regs (issue before B so A-gen's wait leaves B in flight)
#pragma unroll
  for (int j = 0; j < 4; ++j) g[j] = ((const float4*)gp)[j];
#pragma unroll
  for (int j = 0; j < 2; ++j)  // B(0) -> Bs[0]
    __builtin_amdgcn_global_load_lds(
        (const __attribute__((address_space(1))) void*)(bg + (size_t)j * 64 * FEAT),
        (__attribute__((address_space(3))) void*)((char*)Bs[0] + j * 4096 + bldo), 16, 0, 0);
  __syncthreads();  // Ps visible; G(0), B(0) drained

  {  // A(0) -> As[0]
    const float* pr = Ps + ah * 16;
    float4 p0 = ((const float4*)pr)[0], p1 = ((const float4*)pr)[1];
    float4 p2 = ((const float4*)pr)[2], p3 = ((const float4*)pr)[3];
    float d0 = p0.x - g[0].x, d1 = p0.y - g[0].y, d2 = p0.z - g[0].z, d3 = p0.w - g[0].w;
    float d4 = p1.x - g[1].x, d5 = p1.y - g[1].y, d6 = p1.z - g[1].z, d7 = p1.w - g[1].w;
    float e0 = p2.x - g[2].x, e1 = p2.y - g[2].y, e2 = p2.z - g[2].z, e3 = p2.w - g[2].w;
    float e4 = p3.x - g[3].x, e5 = p3.y - g[3].y, e6 = p3.z - g[3].z, e7 = p3.w - g[3].w;
    uint4 ua, ub;
    ua.x = (unsigned int)f2h_u(d0 * d0) | ((unsigned int)f2h_u(d1 * d1) << 16);
    ua.y = (unsigned int)f2h_u(d2 * d2) | ((unsigned int)f2h_u(d3 * d3) << 16);
    ua.z = (unsigned int)f2h_u(d4 * d4) | ((unsigned int)f2h_u(d5 * d5) << 16);
    ua.w = (unsigned int)f2h_u(d6 * d6) | ((unsigned int)f2h_u(d7 * d7) << 16);
    ub.x = (unsigned int)f2h_u(e0 * e0) | ((unsigned int)f2h_u(e1 * e1) << 16);
    ub.y = (unsigned int)f2h_u(e2 * e2) | ((unsigned int)f2h_u(e3 * e3) << 16);
    ub.z = (unsigned int)f2h_u(e4 * e4) | ((unsigned int)f2h_u(e5 * e5) << 16);
    ub.w = (unsigned int)f2h_u(e6 * e6) | ((unsigned int)f2h_u(e7 * e7) << 16);
    unsigned short* ab = As[0] + arow * 32;
    *(uint4*)(ab + aslot0 * 8) = ua;
    *(uint4*)(ab + (aslot0 ^ 1) * 8) = ub;
  }
  __syncthreads();  // A(0) visible

  f32x4 acc[4][4];
#pragma unroll
  for (int mi = 0; mi < 4; ++mi)
#pragma unroll
    for (int ni = 0; ni < 4; ++ni) acc[mi][ni] = (f32x4){0.f, 0.f, 0.f, 0.f};

  const int wm = (wave & 1) * 64, wn = (wave >> 1) * 64;
  const int frow = lane & 15, fk = lane >> 4;
  const int fslot = fk ^ ((frow >> 1) & 3);  // (row>>1)&3 == (frow>>1)&3 for all frag rows

  // ---- main loop: 64 K-steps, one barrier each ----
  int cur = 0;
  for (int t = 0; t < 64; ++t) {
    const int k0 = t * 32;
    const bool hn = (t < 63);
    float4 pn0, pn1, pn2, pn3;

    if (hn) {
      // 1. G(t+1) -> regs (consumed after MFMA; vmcnt wait lands under its shadow)
      const float* gn = gp + k0 + 32;
#pragma unroll
      for (int j = 0; j < 4; ++j) g[j] = ((const float4*)gn)[j];
      // 2. B(t+1) -> Bs[cur^1] (drained by end-of-iteration barrier)
#pragma unroll
      for (int j = 0; j < 2; ++j)
        __builtin_amdgcn_global_load_lds(
            (const __attribute__((address_space(1))) void*)(bg + k0 + 32 + (size_t)j * 64 * FEAT),
            (__attribute__((address_space(3))) void*)((char*)Bs[cur ^ 1] + j * 4096 + bldo), 16, 0, 0);
      // 3. P chunk(t+1)
      const float* prn = Ps + k0 + 32 + ah * 16;
      pn0 = ((const float4*)prn)[0]; pn1 = ((const float4*)prn)[1];
      pn2 = ((const float4*)prn)[2]; pn3 = ((const float4*)prn)[3];
    }

    // 4. fragments + MFMA on buffer `cur`
    __builtin_amdgcn_s_setprio(1);
    {
      f16x8 af[4], bf[4];
#pragma unroll
      for (int mi = 0; mi < 4; ++mi)
        af[mi] = *(const f16x8*)(As[cur] + (wm + mi * 16 + frow) * 32 + fslot * 8);
#pragma unroll
      for (int ni = 0; ni < 4; ++ni)
        bf[ni] = *(const f16x8*)(Bs[cur] + (wn + ni * 16 + frow) * 32 + fslot * 8);
#pragma unroll
      for (int mi = 0; mi < 4; ++mi)
#pragma unroll
        for (int ni = 0; ni < 4; ++ni)
          acc[mi][ni] = __builtin_amdgcn_mfma_f32_16x16x32_f16(af[mi], bf[ni], acc[mi][ni], 0, 0, 0);
    }
    __builtin_amdgcn_s_setprio(0);

    // 5. A-gen(t+1) -> As[cur^1] (under the MFMA shadow of other blocks)
    if (hn) {
      float d0 = pn0.x - g[0].x, d1 = pn0.y - g[0].y, d2 = pn0.z - g[0].z, d3 = pn0.w - g[0].w;
      float d4 = pn1.x - g[1].x, d5 = pn1.y - g[1].y, d6 = pn1.z - g[1].z, d7 = pn1.w - g[1].w;
      float e0 = pn2.x - g[2].x, e1 = pn2.y - g[2].y, e2 = pn2.z - g[2].z, e3 = pn2.w - g[2].w;
      float e4 = pn3.x - g[3].x, e5 = pn3.y - g[3].y, e6 = pn3.z - g[3].z, e7 = pn3.w - g[3].w;
      uint4 ua, ub;
      ua.x = (unsigned int)f2h_u(d0 * d0) | ((unsigned int)f2h_u(d1 * d1) << 16);
      ua.y = (unsigned int)f2h_u(d2 * d2) | ((unsigned int)f2h_u(d3 * d3) << 16);
      ua.z = (unsigned int)f2h_u(d4 * d4) | ((unsigned int)f2h_u(d5 * d5) << 16);
      ua.w = (unsigned int)f2h_u(d6 * d6) | ((unsigned int)f2h_u(d7 * d7) << 16);
      ub.x = (unsigned int)f2h_u(e0 * e0) | ((unsigned int)f2h_u(e1 * e1) << 16);
      ub.y = (unsigned int)f2h_u(e2 * e2) | ((unsigned int)f2h_u(e3 * e3) << 16);
      ub.z = (unsigned int)f2h_u(e4 * e4) | ((unsigned int)f2h_u(e5 * e5) << 16);
      ub.w = (unsigned int)f2h_u(e6 * e6) | ((unsigned int)f2h_u(e7 * e7) << 16);
      unsigned short* ab = As[cur ^ 1] + arow * 32;
      *(uint4*)(ab + aslot0 * 8) = ua;
      *(uint4*)(ab + (aslot0 ^ 1) * 8) = ub;
    }

    __syncthreads();  // single drain point: B(t+1) landed, A(t+1) visible
    cur ^= 1;
  }

  // epilogue: C/D layout col=lane&15, row=(lane>>4)*4+reg; undo WSCALE, add b'
  const int col0 = ntile * 128 + wn + (lane & 15);
  const int row0 = mtile * 128 + wm + ((lane >> 4) << 2);
#pragma unroll
  for (int ni = 0; ni < 4; ++ni) {
    int col = col0 + ni * 16;
    if (col >= NCLS) continue;
    float bv = bp[col];
#pragma unroll
    for (int mi = 0; mi < 4; ++mi) {
      int row = row0 + mi * 16;
#pragma unroll
      for (int r = 0; r < 4; ++r)
        out[(size_t)(row + r) * NCLS + col] = acc[mi][ni][r] * (1.0f / WSCALE) + bv;
    }
  }
}

// ---------------------------------------------------------------------------
extern "C" void kernel_launch(void* const* d_in, const int* in_sizes, int n_in,
                              void* d_out, int out_size, void* d_ws, size_t ws_size,
                              hipStream_t stream) {
  const float* P = (const float*)d_in[0];
  const float* G = (const float*)d_in[1];
  const float* gamma = (const float*)d_in[2];
  const float* beta = (const float*)d_in[3];
  const float* W = (const float*)d_in[4];
  const float* b = (const float*)d_in[5];
  float* out = (float*)d_out;

  float* st = (float*)d_ws;                           // s[2048], t[2048]
  float* bp = st + 2 * FEAT;                          // b'[768]
  unsigned short* Wp = (unsigned short*)(bp + NPAD);  // f16 W' [768, 2048]

  hipLaunchKernelGGL(stats_kernel, dim3(256), dim3(256), 0, stream, P, G, gamma, beta, st);
  hipLaunchKernelGGL(prepw_kernel, dim3(NPAD), dim3(256), 0, stream, W, b, st, Wp, bp);
  hipLaunchKernelGGL(gemm_fused_kernel, dim3(128, 6), dim3(256), 0, stream, P, G, Wp, bp, out);
}

// Round 5
// 164.558 us; speedup vs baseline: 1.2437x; 1.0151x over previous
//
#include <hip/hip_runtime.h>
#include <hip/hip_bf16.h>
#include <hip/hip_fp16.h>

#define FEAT 2048
#define NCLS 751
#define NPAD 768
#define NPRB 64
#define NGAL 256
#define WSCALE 256.0f

typedef _Float16 f16x8 __attribute__((ext_vector_type(8)));
typedef float f32x4 __attribute__((ext_vector_type(4)));

__device__ __forceinline__ unsigned short f2h_u(float x) {
  union { _Float16 h; unsigned short u; } v;
  v.h = (_Float16)x;
  return v.u;
}

// ---------------------------------------------------------------------------
// Kernel 1: per-feature moments -> BN scale s[f], shift t[f].
// 256 blocks x (8 features x 32 row-lanes).
// mean[f] = M2p - 2 M1p M1g + M2g ; E[d^2] = M4p - 4M3p M1g + 6M2p M2g - 4M1p M3g + M4g
// ---------------------------------------------------------------------------
__global__ __launch_bounds__(256)
void stats_kernel(const float* __restrict__ P, const float* __restrict__ G,
                  const float* __restrict__ gamma, const float* __restrict__ beta,
                  float* __restrict__ st) {
  const int t = threadIdx.x;
  const int fx = t & 7, ry = t >> 3;          // 8 features x 32 row-lanes
  const int f = blockIdx.x * 8 + fx;
  float a1 = 0, a2 = 0, a3 = 0, a4 = 0;
#pragma unroll
  for (int r = ry; r < NPRB; r += 32) {       // 2 iters
    float x = P[r * FEAT + f], x2 = x * x;
    a1 += x; a2 += x2; a3 += x2 * x; a4 += x2 * x2;
  }
  float b1 = 0, b2 = 0, b3 = 0, b4 = 0;
#pragma unroll
  for (int r = ry; r < NGAL; r += 32) {       // 8 iters
    float x = G[r * FEAT + f], x2 = x * x;
    b1 += x; b2 += x2; b3 += x2 * x; b4 += x2 * x2;
  }
  __shared__ float red[8][32][8];   // [moment][ry][fx]
  __shared__ float red2[8][4][8];   // [moment][quarter][fx]
  float vals[8] = {a1, a2, a3, a4, b1, b2, b3, b4};
#pragma unroll
  for (int m = 0; m < 8; ++m) red[m][ry][fx] = vals[m];
  __syncthreads();
  {
    int m = t >> 5, q = (t >> 3) & 3, fx2 = t & 7;
    float s = 0.f;
#pragma unroll
    for (int r = 0; r < 8; ++r) s += red[m][q * 8 + r][fx2];
    red2[m][q][fx2] = s;
  }
  __syncthreads();
  if (t < 8) {
    float mm[8];
#pragma unroll
    for (int m = 0; m < 8; ++m)
      mm[m] = red2[m][0][t] + red2[m][1][t] + red2[m][2][t] + red2[m][3][t];
    float M1p = mm[0] * (1.f / NPRB), M2p = mm[1] * (1.f / NPRB);
    float M3p = mm[2] * (1.f / NPRB), M4p = mm[3] * (1.f / NPRB);
    float M1g = mm[4] * (1.f / NGAL), M2g = mm[5] * (1.f / NGAL);
    float M3g = mm[6] * (1.f / NGAL), M4g = mm[7] * (1.f / NGAL);
    float mean = M2p - 2.f * M1p * M1g + M2g;
    float Ed2 = M4p - 4.f * M3p * M1g + 6.f * M2p * M2g - 4.f * M1p * M3g + M4g;
    float var = Ed2 - mean * mean;
    int ff = blockIdx.x * 8 + t;
    float sv = gamma[ff] / sqrtf(var + 1e-5f);
    st[ff] = sv;
    st[FEAT + ff] = beta[ff] - mean * sv;  // t[f]
  }
}

// ---------------------------------------------------------------------------
// Kernel 2 (fused): per class c:
//   Wp[c,f] = W[c,f] * s[f] * WSCALE (f16), bp[c] = b[c] + sum_f t[f] W[c,f]
// ---------------------------------------------------------------------------
__global__ void prepw_kernel(const float* __restrict__ W, const float* __restrict__ b,
                             const float* __restrict__ st,
                             unsigned short* __restrict__ Wp, float* __restrict__ bp) {
  int c = blockIdx.x;
  int f = threadIdx.x * 8;
  float4 w0 = make_float4(0.f, 0.f, 0.f, 0.f), w1 = w0;
  if (c < NCLS) {
    const float4* wsrc = (const float4*)(W + (size_t)c * FEAT + f);
    w0 = wsrc[0]; w1 = wsrc[1];
  }
  const float4* s4 = (const float4*)(st + f);
  float4 s0 = s4[0], s1 = s4[1];
  const float4* t4 = (const float4*)(st + FEAT + f);
  float4 t0 = t4[0], t1 = t4[1];
  uint4 u;
  u.x = (unsigned int)f2h_u(w0.x * s0.x * WSCALE) | ((unsigned int)f2h_u(w0.y * s0.y * WSCALE) << 16);
  u.y = (unsigned int)f2h_u(w0.z * s0.z * WSCALE) | ((unsigned int)f2h_u(w0.w * s0.w * WSCALE) << 16);
  u.z = (unsigned int)f2h_u(w1.x * s1.x * WSCALE) | ((unsigned int)f2h_u(w1.y * s1.y * WSCALE) << 16);
  u.w = (unsigned int)f2h_u(w1.z * s1.z * WSCALE) | ((unsigned int)f2h_u(w1.w * s1.w * WSCALE) << 16);
  *(uint4*)(Wp + (size_t)c * FEAT + f) = u;
  float acc = t0.x * w0.x + t0.y * w0.y + t0.z * w0.z + t0.w * w0.w +
              t1.x * w1.x + t1.y * w1.y + t1.z * w1.z + t1.w * w1.w;
#pragma unroll
  for (int off = 32; off > 0; off >>= 1) acc += __shfl_down(acc, off, 64);
  __shared__ float r[4];
  int wave = threadIdx.x >> 6, lane = threadIdx.x & 63;
  if (lane == 0) r[wave] = acc;
  __syncthreads();
  if (threadIdx.x == 0) bp[c] = (c < NCLS ? b[c] : 0.f) + r[0] + r[1] + r[2] + r[3];
}

// ---------------------------------------------------------------------------
// Kernel 3 (fused GEMM): out = BN((P-G)^2) @ W'^T + b'.
// M=16384, N=768, K=2048. Tile 128x192, BK=32, 512 threads (8 waves, wave
// tile 64x48, acc[4][3]). Grid 128x4 = 512 blocks = EXACTLY 2 blk/CU
// (balanced, single round), 16 waves/CU = 4/SIMD.
// Round-4 lesson: conflicts fixed but dur flat -> LDS instr count + wave
// depth were the limit (12 waves, 14 b128/wave/step). Now 8 b128/wave/step
// (4 af + 3 bf + 1 A-write), P read from GLOBAL (L1-broadcast, off the LDS
// pipe), 2x8KB A + 2x12KB B = 40KB LDS.
// Per K-step (ONE barrier): load G/P(t+1) to regs + issue B(t+1)
// global_load_lds into buf^1; frags+MFMA on buf (setprio); A-gen(t+1) ->
// ds_write buf^1 (G/P vmcnt drains here, under MFMA shadow); __syncthreads.
// Swizzle (64B rows, quad = 4*(row&1)+slot): slot = chunk ^ ((row>>1)&3).
//   A-write: thread t -> row t>>2, chunk t&3 -> slot (t&3)^((t>>3)&3):
//            lanes 0..7 hit quads 0..7 exactly once.
//   B gload: dest linear; source chunk (lane&3)^((lane>>3)&3) (instr-index
//            independent since i*16 contributes 0 mod 4 to (row>>1)&3).
//   Frag read: fslot = fk ^ ((frow>>1)&3)  (wm,wn,ni*16 all ≡0 mod 4 там).
// ---------------------------------------------------------------------------
__global__ __launch_bounds__(512, 4)
void gemm_fused_kernel(const float* __restrict__ P, const float* __restrict__ G,
                       const unsigned short* __restrict__ Wp,
                       const float* __restrict__ bp, float* __restrict__ out) {
  __shared__ unsigned short As[2][128 * 32];  // 2 x 8 KB
  __shared__ unsigned short Bs[2][192 * 32];  // 2 x 12 KB

  const int tid = threadIdx.x;
  const int lane = tid & 63, wave = tid >> 6;  // 8 waves
  const int mtile = blockIdx.x, ntile = blockIdx.y;
  const int p = mtile >> 1;

  // A-gen roles: thread -> row = tid>>2 (0..127), global chunk = tid&3.
  const int arow = tid >> 2, ach = tid & 3;
  const int aoff = arow * 32 + ((ach ^ ((arow >> 1) & 3)) * 8);  // swizzled dest
  const float* gp = G + (size_t)((mtile & 1) * 128 + arow) * FEAT + ach * 8;
  const float* pp = P + (size_t)p * FEAT + ach * 8;  // L1-broadcast source

  // B staging: instr i (= wave, and 8+wave for wave<4) covers rows i*16+(lane>>2).
  const int bch = (lane & 3) ^ ((lane >> 3) & 3);  // pre-swizzled source chunk
  const unsigned short* bg0 =
      Wp + (size_t)(ntile * 192 + wave * 16 + (lane >> 2)) * FEAT + bch * 8;
  const unsigned short* bg1 =
      Wp + (size_t)(ntile * 192 + 128 + wave * 16 + (lane >> 2)) * FEAT + bch * 8;
  const int bdo0 = wave * 1024;         // dest byte offset (HW adds lane*16)
  const int bdo1 = 8192 + wave * 1024;  // second instr (wave<4 only)

  // ---- prologue: tile 0 ----
  float4 ga, gb, pa, pb;
  ga = ((const float4*)gp)[0]; gb = ((const float4*)gp)[1];
  pa = ((const float4*)pp)[0]; pb = ((const float4*)pp)[1];
  __builtin_amdgcn_global_load_lds(
      (const __attribute__((address_space(1))) void*)bg0,
      (__attribute__((address_space(3))) void*)((char*)Bs[0] + bdo0), 16, 0, 0);
  if (wave < 4)
    __builtin_amdgcn_global_load_lds(
        (const __attribute__((address_space(1))) void*)bg1,
        (__attribute__((address_space(3))) void*)((char*)Bs[0] + bdo1), 16, 0, 0);
  {  // A(0) -> As[0]  (compiler inserts vmcnt wait for ga..pb before use)
    float d0 = pa.x - ga.x, d1 = pa.y - ga.y, d2 = pa.z - ga.z, d3 = pa.w - ga.w;
    float d4 = pb.x - gb.x, d5 = pb.y - gb.y, d6 = pb.z - gb.z, d7 = pb.w - gb.w;
    uint4 u;
    u.x = (unsigned int)f2h_u(d0 * d0) | ((unsigned int)f2h_u(d1 * d1) << 16);
    u.y = (unsigned int)f2h_u(d2 * d2) | ((unsigned int)f2h_u(d3 * d3) << 16);
    u.z = (unsigned int)f2h_u(d4 * d4) | ((unsigned int)f2h_u(d5 * d5) << 16);
    u.w = (unsigned int)f2h_u(d6 * d6) | ((unsigned int)f2h_u(d7 * d7) << 16);
    *(uint4*)(As[0] + aoff) = u;
  }
  __syncthreads();  // A(0) visible; B(0) drained (vmcnt0 at barrier)

  f32x4 acc[4][3];
#pragma unroll
  for (int mi = 0; mi < 4; ++mi)
#pragma unroll
    for (int ni = 0; ni < 3; ++ni) acc[mi][ni] = (f32x4){0.f, 0.f, 0.f, 0.f};

  const int wm = (wave & 1) * 64, wn = (wave >> 1) * 48;
  const int frow = lane & 15, fk = lane >> 4;
  const int fslot = fk ^ ((frow >> 1) & 3);

  // ---- main loop: 64 K-steps, one barrier each ----
  int cur = 0;
  for (int t = 0; t < 64; ++t) {
    const int k0 = t * 32;
    const bool hn = (t < 63);

    if (hn) {
      // 1. G/P(t+1) -> regs (consumed in phase 5, under the MFMA shadow)
      const float* gn = gp + k0 + 32;
      const float* pn = pp + k0 + 32;
      ga = ((const float4*)gn)[0]; gb = ((const float4*)gn)[1];
      pa = ((const float4*)pn)[0]; pb = ((const float4*)pn)[1];
      // 2. B(t+1) -> Bs[cur^1] (drained by end-of-iteration barrier)
      __builtin_amdgcn_global_load_lds(
          (const __attribute__((address_space(1))) void*)(bg0 + k0 + 32),
          (__attribute__((address_space(3))) void*)((char*)Bs[cur ^ 1] + bdo0), 16, 0, 0);
      if (wave < 4)
        __builtin_amdgcn_global_load_lds(
            (const __attribute__((address_space(1))) void*)(bg1 + k0 + 32),
            (__attribute__((address_space(3))) void*)((char*)Bs[cur ^ 1] + bdo1), 16, 0, 0);
    }

    // 3. fragments + MFMA on buffer `cur`
    __builtin_amdgcn_s_setprio(1);
    {
      f16x8 af[4], bf[3];
#pragma unroll
      for (int mi = 0; mi < 4; ++mi)
        af[mi] = *(const f16x8*)(As[cur] + (wm + mi * 16 + frow) * 32 + fslot * 8);
#pragma unroll
      for (int ni = 0; ni < 3; ++ni)
        bf[ni] = *(const f16x8*)(Bs[cur] + (wn + ni * 16 + frow) * 32 + fslot * 8);
#pragma unroll
      for (int mi = 0; mi < 4; ++mi)
#pragma unroll
        for (int ni = 0; ni < 3; ++ni)
          acc[mi][ni] = __builtin_amdgcn_mfma_f32_16x16x32_f16(af[mi], bf[ni], acc[mi][ni], 0, 0, 0);
    }
    __builtin_amdgcn_s_setprio(0);

    // 4. A-gen(t+1) -> As[cur^1] (G/P vmcnt drains here)
    if (hn) {
      float d0 = pa.x - ga.x, d1 = pa.y - ga.y, d2 = pa.z - ga.z, d3 = pa.w - ga.w;
      float d4 = pb.x - gb.x, d5 = pb.y - gb.y, d6 = pb.z - gb.z, d7 = pb.w - gb.w;
      uint4 u;
      u.x = (unsigned int)f2h_u(d0 * d0) | ((unsigned int)f2h_u(d1 * d1) << 16);
      u.y = (unsigned int)f2h_u(d2 * d2) | ((unsigned int)f2h_u(d3 * d3) << 16);
      u.z = (unsigned int)f2h_u(d4 * d4) | ((unsigned int)f2h_u(d5 * d5) << 16);
      u.w = (unsigned int)f2h_u(d6 * d6) | ((unsigned int)f2h_u(d7 * d7) << 16);
      *(uint4*)(As[cur ^ 1] + aoff) = u;
    }

    __syncthreads();  // single drain point: B(t+1) landed, A(t+1) visible
    cur ^= 1;
  }

  // epilogue: C/D layout col=lane&15, row=(lane>>4)*4+reg; undo WSCALE, add b'
  const int col0 = ntile * 192 + wn + (lane & 15);
  const int row0 = mtile * 128 + wm + ((lane >> 4) << 2);
#pragma unroll
  for (int ni = 0; ni < 3; ++ni) {
    int col = col0 + ni * 16;
    if (col >= NCLS) continue;
    float bv = bp[col];
#pragma unroll
    for (int mi = 0; mi < 4; ++mi) {
      int row = row0 + mi * 16;
#pragma unroll
      for (int r = 0; r < 4; ++r)
        out[(size_t)(row + r) * NCLS + col] = acc[mi][ni][r] * (1.0f / WSCALE) + bv;
    }
  }
}

// ---------------------------------------------------------------------------
extern "C" void kernel_launch(void* const* d_in, const int* in_sizes, int n_in,
                              void* d_out, int out_size, void* d_ws, size_t ws_size,
                              hipStream_t stream) {
  const float* P = (const float*)d_in[0];
  const float* G = (const float*)d_in[1];
  const float* gamma = (const float*)d_in[2];
  const float* beta = (const float*)d_in[3];
  const float* W = (const float*)d_in[4];
  const float* b = (const float*)d_in[5];
  float* out = (float*)d_out;

  float* st = (float*)d_ws;                           // s[2048], t[2048]
  float* bp = st + 2 * FEAT;                          // b'[768]
  unsigned short* Wp = (unsigned short*)(bp + NPAD);  // f16 W' [768, 2048]

  hipLaunchKernelGGL(stats_kernel, dim3(256), dim3(256), 0, stream, P, G, gamma, beta, st);
  hipLaunchKernelGGL(prepw_kernel, dim3(NPAD), dim3(256), 0, stream, W, b, st, Wp, bp);
  hipLaunchKernelGGL(gemm_fused_kernel, dim3(128, 4), dim3(512), 0, stream, P, G, Wp, bp, out);
}